// Round 5
// baseline (150.855 us; speedup 1.0000x reference)
//
#include <hip/hip_runtime.h>
#include <hip/hip_bf16.h>

#define NN 128
#define CC 1001
#define RR 51
#define KK 10
#define NK (NN*KK)              // 1280
#define BT_ELEMS (NN*KK*NN*KK) // 1,638,400
#define NROWS (CC*CC)           // 1,002,001 relmat rows
#define MAXO 32                 // max occurrences of a class in the 1280 labels
#define W_BIN_C 1.0f
#define MIX_C 10000.0f

typedef float f4_t __attribute__((ext_vector_type(4)));
typedef f4_t f4u __attribute__((aligned(4)));   // 4-byte-aligned float4 load

// ---------------- prep: exp(rel_scores) + top-k + inverse class map ----------------
// blocks 0..103: exp_rel (208,896 f4 elems, grid-stride)
// blocks 104..231: top-k for row a=blk-104 (1 wave), fused list build via atomics.
__global__ __launch_bounds__(256) void prep_kernel(const float* __restrict__ roi,
                                                   const float* __restrict__ rel,
                                                   float* __restrict__ exp_rel,
                                                   int* __restrict__ labels,
                                                   float* __restrict__ unary,
                                                   int* __restrict__ count,
                                                   int* __restrict__ list) {
    int blk = blockIdx.x;
    if (blk < 104) {
        const f4_t* in4 = (const f4_t*)rel;
        f4_t* out4 = (f4_t*)exp_rel;
        for (int i = blk * 256 + threadIdx.x; i < (NN * NN * RR) / 4; i += 104 * 256) {
            f4_t v = in4[i];
            f4_t e;
            e.x = expf(v.x); e.y = expf(v.y); e.z = expf(v.z); e.w = expf(v.w);
            out4[i] = e;
        }
        return;
    }
    int a = blk - 104;
    int lane = threadIdx.x;
    if (lane >= 64) return;
    const float* rowp = roi + a * CC;
    float v[16];
    #pragma unroll
    for (int j = 0; j < 16; ++j) {
        int c = lane + 64 * j;
        v[j] = (c < CC) ? rowp[c] : -1e30f;
    }
    for (int k = 0; k < KK; ++k) {
        float bv = v[0]; int bj = 0;
        #pragma unroll
        for (int j = 1; j < 16; ++j) if (v[j] > bv) { bv = v[j]; bj = j; }  // ascending: lowest idx on tie
        int bc = lane + 64 * bj;
        #pragma unroll
        for (int m = 32; m > 0; m >>= 1) {
            float v2 = __shfl_xor(bv, m, 64);
            int   c2 = __shfl_xor(bc, m, 64);
            if (v2 > bv || (v2 == bv && c2 < bc)) { bv = v2; bc = c2; }
        }
        if (lane == (bc & 63)) {
            int j = bc >> 6;
            #pragma unroll
            for (int jj = 0; jj < 16; ++jj) if (jj == j) v[jj] = -1e30f;
        }
        if (lane == 0) {
            labels[a * KK + k] = bc;
            unary[a * KK + k]  = logf(bv);
            int slot = atomicAdd(&count[bc], 1);
            if (slot < MAXO) list[bc * MAXO + slot] = (a << 4) | k;
        }
    }
}

// ---------------- streaming scatter: sweep relmat rows in address order ----------------
// 8-lane group per row R=(x,y). Skip if class x or y unused (row never fetched).
// Active: load 204B row (2 f4/lane), then for each ((a,k),(b,l)) in list[x]xlist[y]:
// load exp_rel[a*128+b] coeffs (L2-hot), dot, 3-step shuffle, scatter 1 float.
__global__ __launch_bounds__(256) void scatter_kernel(const float* __restrict__ relmat,
                                                      const float* __restrict__ exp_rel,
                                                      const int* __restrict__ count,
                                                      const int* __restrict__ list,
                                                      float* __restrict__ raw) {
    int t = threadIdx.x;
    int g = t >> 3, sub = t & 7;
    int R = blockIdx.x * 32 + g;
    if (R >= NROWS) return;
    int x = R / CC, y = R % CC;
    int nx = count[x]; if (nx == 0) return;
    int ny = count[y]; if (ny == 0) return;
    if (nx > MAXO) nx = MAXO;
    if (ny > MAXO) ny = MAXO;

    bool act0 = sub < 7, act1 = sub < 6;
    int r0 = (sub < 6) ? sub * 8 : 47;   // lane6: r=47..50, x zeroed (47 counted by lane5)
    int r1 = sub * 8 + 4;
    f4_t zero; zero.x = zero.y = zero.z = zero.w = 0.f;
    const float* rowp = relmat + R * RR;
    f4_t c0 = act0 ? *(const f4u*)(rowp + r0) : zero;
    f4_t c1 = act1 ? *(const f4u*)(rowp + r1) : zero;
    if (sub == 6) c0.x = 0.f;

    for (int i = 0; i < nx; ++i) {
        int ea = list[x * MAXO + i];
        int a = ea >> 4, k = ea & 15;
        int obase = (a * KK + k) * NK;
        const float* epbase = exp_rel + a * (NN * RR);
        for (int j = 0; j < ny; ++j) {
            int eb = list[y * MAXO + j];
            int b = eb >> 4, l = eb & 15;
            const float* ep = epbase + b * RR;
            f4_t e0 = act0 ? *(const f4u*)(ep + r0) : zero;
            f4_t e1 = act1 ? *(const f4u*)(ep + r1) : zero;
            float s = c0.x*e0.x + c0.y*e0.y + c0.z*e0.z + c0.w*e0.w
                    + c1.x*e1.x + c1.y*e1.y + c1.z*e1.z + c1.w*e1.w;
            s += __shfl_xor(s, 4, 64);
            s += __shfl_xor(s, 2, 64);
            s += __shfl_xor(s, 1, 64);
            if (sub == 0) raw[obase + b * KK + l] = s;
        }
    }
}

// ---------------- bt = log(0.5*(raw + raw^T)); zero when a==b (in place) ----------------
__global__ __launch_bounds__(256) void symlog_kernel(float* __restrict__ bt) {
    int i = blockIdx.x * 256 + threadIdx.x;
    int l = i % KK;
    int b = (i / KK) % NN;
    int k = (i / (KK * NN)) % KK;
    int a = i / (KK * NN * KK);
    if (a > b) return;
    if (a == b) { bt[i] = 0.0f; return; }
    int j = ((b * KK + l) * NN + a) * KK + k;
    float xx = bt[i], yy = bt[j];
    float v = logf(0.5f * (xx + yy));
    bt[i] = v;
    bt[j] = v;
}

// ---------------- mean-field round: 10 waves, wave k owns row k ----------------
__global__ __launch_bounds__(640) void round_kernel(const float* __restrict__ bt,
                                                    const float* __restrict__ unary,
                                                    const float* __restrict__ Qin,
                                                    float* __restrict__ Qout,
                                                    int uniform) {
    int a = blockIdx.x, t = threadIdx.x;
    int wave = t >> 6, lane = t & 63;
    __shared__ float sQ[NK];
    __shared__ float smsg[KK];
    if (!uniform && t < NK / 4) ((f4_t*)sQ)[t] = ((const f4_t*)Qin)[t];
    __syncthreads();
    const f4_t* row = (const f4_t*)(bt + (a * KK + wave) * NK);
    float acc = 0.f;
    if (uniform) {
        #pragma unroll
        for (int j = 0; j < 5; ++j) {
            f4_t r = row[lane + 64 * j];
            acc += r.x + r.y + r.z + r.w;
        }
        acc *= (1.0f / (float)KK);
    } else {
        const f4_t* q4 = (const f4_t*)sQ;
        #pragma unroll
        for (int j = 0; j < 5; ++j) {
            f4_t r = row[lane + 64 * j];
            f4_t q = q4[lane + 64 * j];
            acc += r.x * q.x + r.y * q.y + r.z * q.z + r.w * q.w;
        }
    }
    #pragma unroll
    for (int m = 32; m > 0; m >>= 1) acc += __shfl_xor(acc, m, 64);
    if (lane == 0) smsg[wave] = acc;
    __syncthreads();
    if (t == 0) {
        float e[KK], m = -1e30f;
        #pragma unroll
        for (int k = 0; k < KK; ++k) {
            float v = W_BIN_C * smsg[k] + unary[a * KK + k];
            e[k] = v;
            if (v > m) m = v;
        }
        float s = 0.f;
        #pragma unroll
        for (int k = 0; k < KK; ++k) { e[k] = expf(e[k] - m); s += e[k]; }
        #pragma unroll
        for (int k = 0; k < KK; ++k) Qout[a * KK + k] = e[k] / s;
    }
}

// ---------------- final round fused with output scatter/mix ----------------
__global__ __launch_bounds__(640) void round_out_kernel(const float* __restrict__ bt,
                                                        const float* __restrict__ unary,
                                                        const float* __restrict__ Qin,
                                                        const float* __restrict__ roi,
                                                        const int* __restrict__ labels,
                                                        float* __restrict__ out) {
    int a = blockIdx.x, t = threadIdx.x;
    int wave = t >> 6, lane = t & 63;
    __shared__ float sQ[NK];
    __shared__ float smsg[KK];
    __shared__ float sq[KK];
    __shared__ int   sL[KK];
    if (t < NK / 4) ((f4_t*)sQ)[t] = ((const f4_t*)Qin)[t];
    if (t >= 320 && t < 320 + KK) sL[t - 320] = labels[a * KK + (t - 320)];
    __syncthreads();
    const f4_t* row = (const f4_t*)(bt + (a * KK + wave) * NK);
    const f4_t* q4  = (const f4_t*)sQ;
    float acc = 0.f;
    #pragma unroll
    for (int j = 0; j < 5; ++j) {
        f4_t r = row[lane + 64 * j];
        f4_t q = q4[lane + 64 * j];
        acc += r.x * q.x + r.y * q.y + r.z * q.z + r.w * q.w;
    }
    #pragma unroll
    for (int m = 32; m > 0; m >>= 1) acc += __shfl_xor(acc, m, 64);
    if (lane == 0) smsg[wave] = acc;
    __syncthreads();
    if (t == 0) {
        float e[KK], m = -1e30f;
        #pragma unroll
        for (int k = 0; k < KK; ++k) {
            float v = W_BIN_C * smsg[k] + unary[a * KK + k];
            e[k] = v;
            if (v > m) m = v;
        }
        float s = 0.f;
        #pragma unroll
        for (int k = 0; k < KK; ++k) { e[k] = expf(e[k] - m); s += e[k]; }
        #pragma unroll
        for (int k = 0; k < KK; ++k) sq[k] = e[k] / s;
    }
    __syncthreads();
    for (int c = t; c < CC; c += 640) {
        float q = 0.f;
        #pragma unroll
        for (int k = 0; k < KK; ++k) if (sL[k] == c) q = sq[k];
        out[a * CC + c] = (roi[a * CC + c] + MIX_C * q) / (1.0f + MIX_C);
    }
}

extern "C" void kernel_launch(void* const* d_in, const int* in_sizes, int n_in,
                              void* d_out, int out_size, void* d_ws, size_t ws_size,
                              hipStream_t stream) {
    const float* roi    = (const float*)d_in[0];  // (128, 1001)
    const float* rel    = (const float*)d_in[1];  // (16384, 51)
    const float* relmat = (const float*)d_in[2];  // (1001, 1001, 51)
    float* out = (float*)d_out;

    // workspace layout (all 16B-aligned); total ~10.0 MB
    char* ws = (char*)d_ws;
    size_t off = 0;
    float* bt      = (float*)(ws + off); off += (size_t)BT_ELEMS * 4;        // 6,553,600
    float* exp_rel = (float*)(ws + off); off += (size_t)NN * NN * RR * 4;    // 3,342,336
    int*   labels  = (int*)(ws + off);   off += NK * 4;
    float* unary   = (float*)(ws + off); off += NK * 4;
    float* QA      = (float*)(ws + off); off += NK * 4;
    float* QB      = (float*)(ws + off); off += NK * 4;
    int*   count   = (int*)(ws + off);   off += ((CC * 4 + 15) / 16) * 16;
    int*   list    = (int*)(ws + off);   off += (size_t)CC * MAXO * 4;       // 128,128

    hipMemsetAsync(count, 0, CC * sizeof(int), stream);
    prep_kernel<<<104 + NN, 256, 0, stream>>>(roi, rel, exp_rel, labels, unary, count, list);
    scatter_kernel<<<(NROWS + 31) / 32, 256, 0, stream>>>(relmat, exp_rel, count, list, bt);
    symlog_kernel<<<BT_ELEMS / 256, 256, 0, stream>>>(bt);
    round_kernel<<<NN, 640, 0, stream>>>(bt, unary, QA, QA, 1);       // round 1: uniform Q
    round_kernel<<<NN, 640, 0, stream>>>(bt, unary, QA, QB, 0);       // round 2
    round_out_kernel<<<NN, 640, 0, stream>>>(bt, unary, QB, roi, labels, out);  // round 3 + mix
}

// Round 6
// 104.408 us; speedup vs baseline: 1.4449x; 1.4449x over previous
//
#include <hip/hip_runtime.h>
#include <hip/hip_bf16.h>

#define NN 128
#define CC 1001
#define RR 51
#define KK 10
#define NK (NN*KK)              // 1280
#define BT_ELEMS (NN*KK*NN*KK) // 1,638,400 = NK*NK
#define W_BIN_C 1.0f
#define MIX_C 10000.0f

typedef float f4_t __attribute__((ext_vector_type(4)));
typedef f4_t f4u __attribute__((aligned(4)));   // 4-byte-aligned float4 load

// ---------------- prep: exp(rel_scores) + top-k (labels, unary, class counts) ----------------
// blocks 0..103: exp_rel (grid-stride over 208,896 f4); blocks 104..231: top-k row a=blk-104.
__global__ __launch_bounds__(256) void prep_kernel(const float* __restrict__ roi,
                                                   const float* __restrict__ rel,
                                                   float* __restrict__ exp_rel,
                                                   int* __restrict__ labels,
                                                   float* __restrict__ unary,
                                                   int* __restrict__ count) {
    int blk = blockIdx.x;
    if (blk < 104) {
        const f4_t* in4 = (const f4_t*)rel;
        f4_t* out4 = (f4_t*)exp_rel;
        for (int i = blk * 256 + threadIdx.x; i < (NN * NN * RR) / 4; i += 104 * 256) {
            f4_t v = in4[i];
            f4_t e;
            e.x = expf(v.x); e.y = expf(v.y); e.z = expf(v.z); e.w = expf(v.w);
            out4[i] = e;
        }
        return;
    }
    int a = blk - 104;
    int lane = threadIdx.x;
    if (lane >= 64) return;
    const float* rowp = roi + a * CC;
    float v[16];
    #pragma unroll
    for (int j = 0; j < 16; ++j) {
        int c = lane + 64 * j;
        v[j] = (c < CC) ? rowp[c] : -1e30f;
    }
    for (int k = 0; k < KK; ++k) {
        float bv = v[0]; int bj = 0;
        #pragma unroll
        for (int j = 1; j < 16; ++j) if (v[j] > bv) { bv = v[j]; bj = j; }  // ascending: lowest idx on tie
        int bc = lane + 64 * bj;
        #pragma unroll
        for (int m = 32; m > 0; m >>= 1) {
            float v2 = __shfl_xor(bv, m, 64);
            int   c2 = __shfl_xor(bc, m, 64);
            if (v2 > bv || (v2 == bv && c2 < bc)) { bv = v2; bc = c2; }
        }
        if (lane == (bc & 63)) {
            int j = bc >> 6;
            #pragma unroll
            for (int jj = 0; jj < 16; ++jj) if (jj == j) v[jj] = -1e30f;
        }
        if (lane == 0) {
            labels[a * KK + k] = bc;
            unary[a * KK + k]  = logf(bv);
            atomicAdd(&count[bc], 1);
        }
    }
}

// ---------------- build E: the 1280 (a,k) entries sorted by class ----------------
// Single block. LDS Hillis-Steele scan over 1024-padded counts, then atomic-cursor
// scatter. Within-class order is arbitrary (doesn't affect any output value).
// E[p] = (class<<11) | (a<<4) | k
__global__ __launch_bounds__(256) void build_kernel(const int* __restrict__ labels,
                                                    const int* __restrict__ count,
                                                    int* __restrict__ E) {
    __shared__ int s[1024];
    __shared__ int cur[CC];
    int t = threadIdx.x;
    #pragma unroll
    for (int j = 0; j < 4; ++j) {
        int i = t + 256 * j;
        s[i] = (i < CC) ? count[i] : 0;
        if (i < CC) cur[i] = 0;
    }
    __syncthreads();
    for (int off = 1; off < 1024; off <<= 1) {
        int v[4];
        #pragma unroll
        for (int j = 0; j < 4; ++j) {
            int i = t + 256 * j;
            v[j] = s[i] + ((i >= off) ? s[i - off] : 0);
        }
        __syncthreads();
        #pragma unroll
        for (int j = 0; j < 4; ++j) s[t + 256 * j] = v[j];
        __syncthreads();
    }
    for (int e = t; e < NK; e += 256) {
        int cls = labels[e];
        int a = e / KK, k = e - a * KK;
        int slot = atomicAdd(&cur[cls], 1);
        int pos = s[cls] - count[cls] + slot;    // exclusive prefix + rank
        E[pos] = (cls << 11) | (a << 4) | k;
    }
}

// ---------------- dots: raw[(a,k),(b,l)] = dot(relmat[cls_p, cls_q, :], exp_rel[a,b,:]) ----------------
// One 8-lane group per dot d in [0, 1280^2): p=d/1280, q=d%1280. E class-sorted =>
// ascending d sweeps relmat rows in ascending address order (streaming), with the
// per-class working set L2-resident and exp_rel[a] slice (26KB) L1-resident.
// Perfectly uniform work per group.
__global__ __launch_bounds__(256) void dots_kernel(const float* __restrict__ relmat,
                                                   const float* __restrict__ exp_rel,
                                                   const int* __restrict__ E,
                                                   float* __restrict__ raw) {
    int t = threadIdx.x;
    int g = t >> 3, sub = t & 7;
    int d = blockIdx.x * 32 + g;
    int p = d / NK;
    int q = d - p * NK;
    int ep = E[p], eq = E[q];
    int cx = ep >> 11, cy = eq >> 11;
    int a = (ep >> 4) & 127, k = ep & 15;
    int b = (eq >> 4) & 127, l = eq & 15;

    bool act0 = sub < 7, act1 = sub < 6;
    int r0 = (sub < 6) ? sub * 8 : 47;     // lane6: r=47..50, x-coeff zeroed (47 counted by lane5)
    int r1 = sub * 8 + 4;
    f4_t zero; zero.x = zero.y = zero.z = zero.w = 0.f;

    const float* rowp = relmat + ((size_t)cx * CC + cy) * RR;
    const float* epp  = exp_rel + (a * NN + b) * RR;
    f4_t c0 = act0 ? *(const f4u*)(rowp + r0) : zero;
    f4_t c1 = act1 ? *(const f4u*)(rowp + r1) : zero;
    f4_t e0 = act0 ? *(const f4u*)(epp + r0) : zero;
    f4_t e1 = act1 ? *(const f4u*)(epp + r1) : zero;
    if (sub == 6) c0.x = 0.f;

    float s = c0.x*e0.x + c0.y*e0.y + c0.z*e0.z + c0.w*e0.w
            + c1.x*e1.x + c1.y*e1.y + c1.z*e1.z + c1.w*e1.w;
    s += __shfl_xor(s, 4, 64);
    s += __shfl_xor(s, 2, 64);
    s += __shfl_xor(s, 1, 64);
    if (sub == 0) raw[(a * KK + k) * NK + b * KK + l] = s;
}

// ---------------- bt = log(0.5*(raw + raw^T)); zero when a==b (in place) ----------------
__global__ __launch_bounds__(256) void symlog_kernel(float* __restrict__ bt) {
    int i = blockIdx.x * 256 + threadIdx.x;
    int l = i % KK;
    int b = (i / KK) % NN;
    int k = (i / (KK * NN)) % KK;
    int a = i / (KK * NN * KK);
    if (a > b) return;
    if (a == b) { bt[i] = 0.0f; return; }
    int j = ((b * KK + l) * NN + a) * KK + k;
    float xx = bt[i], yy = bt[j];
    float v = logf(0.5f * (xx + yy));
    bt[i] = v;
    bt[j] = v;
}

// ---------------- mean-field round: 10 waves, wave k owns row k ----------------
__global__ __launch_bounds__(640) void round_kernel(const float* __restrict__ bt,
                                                    const float* __restrict__ unary,
                                                    const float* __restrict__ Qin,
                                                    float* __restrict__ Qout,
                                                    int uniform) {
    int a = blockIdx.x, t = threadIdx.x;
    int wave = t >> 6, lane = t & 63;
    __shared__ float sQ[NK];
    __shared__ float smsg[KK];
    if (!uniform && t < NK / 4) ((f4_t*)sQ)[t] = ((const f4_t*)Qin)[t];
    __syncthreads();
    const f4_t* row = (const f4_t*)(bt + (a * KK + wave) * NK);
    float acc = 0.f;
    if (uniform) {
        #pragma unroll
        for (int j = 0; j < 5; ++j) {
            f4_t r = row[lane + 64 * j];
            acc += r.x + r.y + r.z + r.w;
        }
        acc *= (1.0f / (float)KK);
    } else {
        const f4_t* q4 = (const f4_t*)sQ;
        #pragma unroll
        for (int j = 0; j < 5; ++j) {
            f4_t r = row[lane + 64 * j];
            f4_t q = q4[lane + 64 * j];
            acc += r.x * q.x + r.y * q.y + r.z * q.z + r.w * q.w;
        }
    }
    #pragma unroll
    for (int m = 32; m > 0; m >>= 1) acc += __shfl_xor(acc, m, 64);
    if (lane == 0) smsg[wave] = acc;
    __syncthreads();
    if (t == 0) {
        float e[KK], m = -1e30f;
        #pragma unroll
        for (int k = 0; k < KK; ++k) {
            float v = W_BIN_C * smsg[k] + unary[a * KK + k];
            e[k] = v;
            if (v > m) m = v;
        }
        float s = 0.f;
        #pragma unroll
        for (int k = 0; k < KK; ++k) { e[k] = expf(e[k] - m); s += e[k]; }
        #pragma unroll
        for (int k = 0; k < KK; ++k) Qout[a * KK + k] = e[k] / s;
    }
}

// ---------------- final round fused with output scatter/mix ----------------
__global__ __launch_bounds__(640) void round_out_kernel(const float* __restrict__ bt,
                                                        const float* __restrict__ unary,
                                                        const float* __restrict__ Qin,
                                                        const float* __restrict__ roi,
                                                        const int* __restrict__ labels,
                                                        float* __restrict__ out) {
    int a = blockIdx.x, t = threadIdx.x;
    int wave = t >> 6, lane = t & 63;
    __shared__ float sQ[NK];
    __shared__ float smsg[KK];
    __shared__ float sq[KK];
    __shared__ int   sL[KK];
    if (t < NK / 4) ((f4_t*)sQ)[t] = ((const f4_t*)Qin)[t];
    if (t >= 320 && t < 320 + KK) sL[t - 320] = labels[a * KK + (t - 320)];
    __syncthreads();
    const f4_t* row = (const f4_t*)(bt + (a * KK + wave) * NK);
    const f4_t* q4  = (const f4_t*)sQ;
    float acc = 0.f;
    #pragma unroll
    for (int j = 0; j < 5; ++j) {
        f4_t r = row[lane + 64 * j];
        f4_t q = q4[lane + 64 * j];
        acc += r.x * q.x + r.y * q.y + r.z * q.z + r.w * q.w;
    }
    #pragma unroll
    for (int m = 32; m > 0; m >>= 1) acc += __shfl_xor(acc, m, 64);
    if (lane == 0) smsg[wave] = acc;
    __syncthreads();
    if (t == 0) {
        float e[KK], m = -1e30f;
        #pragma unroll
        for (int k = 0; k < KK; ++k) {
            float v = W_BIN_C * smsg[k] + unary[a * KK + k];
            e[k] = v;
            if (v > m) m = v;
        }
        float s = 0.f;
        #pragma unroll
        for (int k = 0; k < KK; ++k) { e[k] = expf(e[k] - m); s += e[k]; }
        #pragma unroll
        for (int k = 0; k < KK; ++k) sq[k] = e[k] / s;
    }
    __syncthreads();
    for (int c = t; c < CC; c += 640) {
        float q = 0.f;
        #pragma unroll
        for (int k = 0; k < KK; ++k) if (sL[k] == c) q = sq[k];
        out[a * CC + c] = (roi[a * CC + c] + MIX_C * q) / (1.0f + MIX_C);
    }
}

extern "C" void kernel_launch(void* const* d_in, const int* in_sizes, int n_in,
                              void* d_out, int out_size, void* d_ws, size_t ws_size,
                              hipStream_t stream) {
    const float* roi    = (const float*)d_in[0];  // (128, 1001)
    const float* rel    = (const float*)d_in[1];  // (16384, 51)
    const float* relmat = (const float*)d_in[2];  // (1001, 1001, 51)
    float* out = (float*)d_out;

    // workspace layout (all 16B-aligned); total ~10 MB
    char* ws = (char*)d_ws;
    size_t off = 0;
    float* bt      = (float*)(ws + off); off += (size_t)BT_ELEMS * 4;        // 6,553,600
    float* exp_rel = (float*)(ws + off); off += (size_t)NN * NN * RR * 4;    // 3,342,336
    int*   labels  = (int*)(ws + off);   off += NK * 4;
    float* unary   = (float*)(ws + off); off += NK * 4;
    float* QA      = (float*)(ws + off); off += NK * 4;
    float* QB      = (float*)(ws + off); off += NK * 4;
    int*   E       = (int*)(ws + off);   off += NK * 4;
    int*   count   = (int*)(ws + off);   off += ((CC * 4 + 15) / 16) * 16;

    hipMemsetAsync(count, 0, CC * sizeof(int), stream);
    prep_kernel<<<104 + NN, 256, 0, stream>>>(roi, rel, exp_rel, labels, unary, count);
    build_kernel<<<1, 256, 0, stream>>>(labels, count, E);
    dots_kernel<<<BT_ELEMS / 32, 256, 0, stream>>>(relmat, exp_rel, E, bt);
    symlog_kernel<<<BT_ELEMS / 256, 256, 0, stream>>>(bt);
    round_kernel<<<NN, 640, 0, stream>>>(bt, unary, QA, QA, 1);       // round 1: uniform Q
    round_kernel<<<NN, 640, 0, stream>>>(bt, unary, QA, QB, 0);       // round 2
    round_out_kernel<<<NN, 640, 0, stream>>>(bt, unary, QB, roi, labels, out);  // round 3 + mix
}